// Round 7
// baseline (660.958 us; speedup 1.0000x reference)
//
#include <hip/hip_runtime.h>

#define NB 64
#define TSTEPS 1024
#define EE 256
#define HH 128
#define MM (NB * TSTEPS)   // 65536 rows
#define GXC 768            // 384 fwd gates + 384 bwd gates
#define BOT 32
#define CH 16              // scan gx-staging chunk (steps)

typedef float    f32x4 __attribute__((ext_vector_type(4)));
typedef _Float16 f16x2 __attribute__((ext_vector_type(2)));
typedef _Float16 f16x4 __attribute__((ext_vector_type(4)));
typedef _Float16 f16x8 __attribute__((ext_vector_type(8)));

#if defined(__has_builtin)
#if __has_builtin(__builtin_amdgcn_rcpf)
#define HAVE_RCPF 1
#endif
#endif

__device__ __forceinline__ float rcpf(float x) {
#ifdef HAVE_RCPF
  return __builtin_amdgcn_rcpf(x);
#else
  return 1.0f / x;
#endif
}

// LDS-only barrier: orders LDS traffic (lgkmcnt) but does NOT drain vmcnt.
#define LDS_BARRIER() asm volatile("s_waitcnt lgkmcnt(0)\ns_barrier" ::: "memory")

// ---------------------------------------------------------------------------
// Kernel A (R7 rewrite): gx[m][g] = sum_e x[m][e]*w_ih[g][e], g over ALL 768
// gate cols. One block = 128 rows x 768 cols: x-tile staged in LDS ONCE (f16,
// 128x264 = 67 KB), weights re-staged per (by,kc) from L2 (768 KB total,
// cache-resident). MFMA operand roles swapped vs R6 (arg0 = weights) so D's
// (quad,reg) axis = g -> 4 consecutive g per lane -> packed f16x4 stores.
// ---------------------------------------------------------------------------
__global__ __launch_bounds__(256, 1) void gx_gemm(
    const float* __restrict__ x, const float* __restrict__ wf,
    const float* __restrict__ wb, _Float16* __restrict__ gx) {
  __shared__ _Float16 As[128 * 264];   // x rows, K=256 + pad 8
  __shared__ _Float16 Bs[128 * 72];    // weight rows, 64-K chunk + pad 8
  const int tid = threadIdx.x;
  const int m0  = blockIdx.x * 128;

  const int lane = tid & 63;
  const int wid  = tid >> 6;
  const int wg = wid & 1, wm = wid >> 1;  // 2x2 wave grid: 64 g x 64 m
  const int l15  = lane & 15;
  const int quad = lane >> 4;
  const int fk   = quad * 8;

  // stage x-tile once: 128 rows x 64 float4
#pragma unroll
  for (int i = 0; i < 32; ++i) {
    int idx = tid + i * 256;          // 0..8191
    int row = idx >> 6;
    int kf  = (idx & 63) * 4;
    float4 av = *(const float4*)(x + (size_t)(m0 + row) * 256 + kf);
    f16x4 ah;
    ah[0] = (_Float16)av.x; ah[1] = (_Float16)av.y;
    ah[2] = (_Float16)av.z; ah[3] = (_Float16)av.w;
    *(f16x4*)&As[row * 264 + kf] = ah;
  }

#pragma unroll 1
  for (int by = 0; by < 6; ++by) {
    const float* wsrc = (by < 3) ? (wf + (size_t)(by * 128) * 256)
                                 : (wb + (size_t)((by - 3) * 128) * 256);
    const int g0 = by * 128;
    f32x4 acc[4][4];   // [tg][tmx]
#pragma unroll
    for (int a = 0; a < 4; ++a)
#pragma unroll
      for (int b = 0; b < 4; ++b) acc[a][b] = (f32x4)0.0f;

#pragma unroll 1
    for (int kc = 0; kc < 4; ++kc) {
      const int k0 = kc * 64;
      __syncthreads();   // protect Bs from previous use (also orders As once)
#pragma unroll
      for (int i = 0; i < 8; ++i) {
        int idx = tid + i * 256;        // 128 rows x 16 float4
        int row = idx >> 4;
        int k4  = (idx & 15) * 4;
        float4 bv = *(const float4*)(wsrc + (size_t)row * 256 + k0 + k4);
        f16x4 bh;
        bh[0] = (_Float16)bv.x; bh[1] = (_Float16)bv.y;
        bh[2] = (_Float16)bv.z; bh[3] = (_Float16)bv.w;
        *(f16x4*)&Bs[row * 72 + k4] = bh;
      }
      __syncthreads();
#pragma unroll
      for (int ks = 0; ks < 2; ++ks) {
        f16x8 wfr[4], xfr[4];
#pragma unroll
        for (int tt = 0; tt < 4; ++tt) {
          wfr[tt] = *(const f16x8*)&Bs[(wg * 64 + tt * 16 + l15) * 72 + ks * 32 + fk];
          xfr[tt] = *(const f16x8*)&As[(wm * 64 + tt * 16 + l15) * 264 + k0 + ks * 32 + fk];
        }
#pragma unroll
        for (int tg = 0; tg < 4; ++tg)
#pragma unroll
          for (int tmx = 0; tmx < 4; ++tmx)
            acc[tg][tmx] = __builtin_amdgcn_mfma_f32_16x16x32_f16(
                wfr[tg], xfr[tmx], acc[tg][tmx], 0, 0, 0);
      }
    }
    // epilogue (regs->global only, no barrier): D[g][m], g=(quad*4+reg),
    // m=lane&15 -> 4 consecutive g per lane -> f16x4 8B store
#pragma unroll
    for (int tg = 0; tg < 4; ++tg)
#pragma unroll
      for (int tmx = 0; tmx < 4; ++tmx) {
        int m = m0 + wm * 64 + tmx * 16 + l15;
        int g = g0 + wg * 64 + tg * 16 + quad * 4;
        f16x4 v;
        v[0] = (_Float16)acc[tg][tmx][0];
        v[1] = (_Float16)acc[tg][tmx][1];
        v[2] = (_Float16)acc[tg][tmx][2];
        v[3] = (_Float16)acc[tg][tmx][3];
        *(f16x4*)&gx[(size_t)m * GXC + g] = v;
      }
  }
}

// ---------------------------------------------------------------------------
// Kernel B: GRU scan — MFMA-broadcast matvec. Unchanged from R6 (WIN).
// ---------------------------------------------------------------------------
__global__ __launch_bounds__(256, 1) void gru_scan(
    const _Float16* __restrict__ gx,
    const float* __restrict__ whf, const float* __restrict__ whb,
    const float* __restrict__ bihf, const float* __restrict__ bhhf,
    const float* __restrict__ bihb, const float* __restrict__ bhhb,
    _Float16* __restrict__ pros) {
  const int bid = blockIdx.x;
  const int dir = bid & 1;
  const int n   = bid >> 1;
  const float* whh = dir ? whb : whf;
  const float* bih = dir ? bihb : bihf;
  const float* bhh = dir ? bhhb : bhhf;

  const int tid  = threadIdx.x;
  const int w    = tid >> 6;            // wave 0..3
  const int lane = tid & 63;
  const int l15  = lane & 15;
  const int quad = lane >> 4;           // 0..3
  const int jj   = (w << 5) | (lane & 31);   // h index; lanes 32-63 replicate

  __shared__ __align__(16) _Float16 hbuf[2][128];
  __shared__ __align__(16) _Float16 gbuf[2][CH * 384];  // 24 KB staging

  // B-frags: w_hh tiles, layout B[nrow = l15][k = quad*8 + j].
  // ti: 0,1 = r tile-pair; 2,3 = z; 4,5 = n.
  f16x8 bfrag[6][4];
#pragma unroll
  for (int ti = 0; ti < 6; ++ti) {
    const int nt  = (ti >> 1) * 8 + 2 * w + (ti & 1);
    const int row = nt * 16 + l15;
#pragma unroll
    for (int kt = 0; kt < 4; ++kt) {
      const int k0 = kt * 32 + quad * 8;
      float4 a = *(const float4*)(whh + (size_t)row * HH + k0);
      float4 b = *(const float4*)(whh + (size_t)row * HH + k0 + 4);
      f16x8 v;
      v[0] = (_Float16)a.x; v[1] = (_Float16)a.y;
      v[2] = (_Float16)a.z; v[3] = (_Float16)a.w;
      v[4] = (_Float16)b.x; v[5] = (_Float16)b.y;
      v[6] = (_Float16)b.z; v[7] = (_Float16)b.w;
      bfrag[ti][kt] = v;
    }
  }
  // biases (redundant across replicas)
  const float br  = bih[jj] + bhh[jj];
  const float bz  = bih[HH + jj] + bhh[HH + jj];
  const float bni = bih[2 * HH + jj];
  const float bnh = bhh[2 * HH + jj];
  const float LOG2E = 1.4426950408889634f;

  if (tid < 128) hbuf[0][tid] = (_Float16)0.f;
  float hprev = 0.f;

  // gx staging: 768 f16x8 units per chunk, 3 per thread
  f16x8 stage[3];
  int su[3], sc8[3];
#pragma unroll
  for (int i = 0; i < 3; ++i) {
    int u = tid + i * 256;
    su[i]  = u / 48;                 // step-in-chunk
    sc8[i] = (u - su[i] * 48) * 8;   // half-offset within the 384-col row
  }
  auto load_chunk = [&](int ch) {
#pragma unroll
    for (int i = 0; i < 3; ++i) {
      int t  = ch * CH + su[i];
      int tt = dir ? (TSTEPS - 1 - t) : t;
      stage[i] = *(const f16x8*)(gx + ((size_t)(n * TSTEPS + tt)) * GXC +
                                 dir * 384 + sc8[i]);
    }
  };
  auto write_chunk = [&](int buf) {
#pragma unroll
    for (int i = 0; i < 3; ++i)
      *(f16x8*)&gbuf[buf][su[i] * 384 + sc8[i]] = stage[i];
  };

  load_chunk(0);
  write_chunk(0);
  LDS_BARRIER();

  const f32x4 zacc = (f32x4)0.0f;
  const int b4 = (lane >> 4) & 1;        // tile-pair select for this lane
  int p = 0;
  const int NCH = TSTEPS / CH;
#pragma unroll 1
  for (int ch = 0; ch < NCH; ++ch) {
    const int buf = ch & 1;
    if (ch + 1 < NCH) load_chunk(ch + 1);  // into regs; retires mid-chunk
#pragma unroll 1
    for (int s = 0; s < CH; ++s) {
      const int t  = ch * CH + s;
      const int tt = dir ? (TSTEPS - 1 - t) : t;
      // gx reads (LDS broadcast, 2-way) — off the critical path
      const _Float16* gr = &gbuf[buf][s * 384];
      const float pxr = -((float)gr[jj] + br) * LOG2E;
      const float pxz = -((float)gr[HH + jj] + bz) * LOG2E;
      const float pxn = (float)gr[2 * HH + jj] + bni;
      // A-frags: h broadcast (4 distinct addresses per wave)
      f16x8 af[4];
#pragma unroll
      for (int kt = 0; kt < 4; ++kt)
        af[kt] = *(const f16x8*)&hbuf[p][kt * 32 + quad * 8];
      // 6 N-tiles x 4 K-tiles of MFMA (M-replicated h)
      f32x4 d[6];
#pragma unroll
      for (int ti = 0; ti < 6; ++ti) {
        d[ti] = __builtin_amdgcn_mfma_f32_16x16x32_f16(af[0], bfrag[ti][0],
                                                       zacc, 0, 0, 0);
#pragma unroll
        for (int kt = 1; kt < 4; ++kt)
          d[ti] = __builtin_amdgcn_mfma_f32_16x16x32_f16(af[kt], bfrag[ti][kt],
                                                         d[ti], 0, 0, 0);
      }
      // per-lane gate sums: tile-pair select by bit4 (all m-replicas equal)
      const float ar = b4 ? d[1][0] : d[0][0];
      const float az = b4 ? d[3][0] : d[2][0];
      const float an = b4 ? d[5][0] : d[4][0];
      // tail (redundant in replica lanes)
      const float rv = rcpf(1.f + __builtin_exp2f(fmaf(ar, -LOG2E, pxr)));
      const float zv = rcpf(1.f + __builtin_exp2f(fmaf(az, -LOG2E, pxz)));
      float na = fmaf(rv, an + bnh, pxn);
      na = fminf(15.f, fmaxf(-15.f, na));
      const float e  = __builtin_exp2f(na * (-2.f * LOG2E));
      const float nn = (1.f - e) * rcpf(1.f + e);
      const float hnew = fmaf(zv, hprev - nn, nn);   // (1-z)*n + z*h
      hprev = hnew;
      if (lane < 32) {
        hbuf[p ^ 1][jj] = (_Float16)hnew;
        pros[((size_t)(n * TSTEPS + tt)) * EE + dir * HH + jj] = (_Float16)hnew;
      }
      if (s == 7 && ch + 1 < NCH) write_chunk(buf ^ 1);  // vmcnt free by now
      LDS_BARRIER();
      p ^= 1;
    }
  }
}

// ---------------------------------------------------------------------------
// Kernel C: out[m][o] = pros[m][:] . w_out[o][:] + b_out[o]
// Unchanged from R6.
// ---------------------------------------------------------------------------
__global__ __launch_bounds__(256) void out_proj(
    const _Float16* __restrict__ pros, const float* __restrict__ wout,
    const float* __restrict__ bout, float* __restrict__ out) {
  __shared__ float wlds[32 * 260];
  const int tid = threadIdx.x;
  const int m0  = blockIdx.x * 256;
#pragma unroll
  for (int i = 0; i < 8; ++i) {
    int f4  = tid + i * 256;   // 0..2047 float4s of w_out
    int col = f4 >> 6;
    int k4  = (f4 & 63) * 4;
    *(float4*)&wlds[col * 260 + k4] = *(const float4*)(wout + (size_t)col * 256 + k4);
  }
  __syncthreads();
  const int rb = tid >> 3;  // 0..31
  const int cg = tid & 7;   // 0..7
  float acc[8][4];
#pragma unroll
  for (int a = 0; a < 8; ++a)
#pragma unroll
    for (int b = 0; b < 4; ++b) acc[a][b] = 0.f;

  for (int kk = 0; kk < 256; kk += 4) {
    float4 wv[4];
#pragma unroll
    for (int cc = 0; cc < 4; ++cc)
      wv[cc] = *(const float4*)&wlds[(cg + 8 * cc) * 260 + kk];
#pragma unroll
    for (int ri = 0; ri < 8; ++ri) {
      f16x4 xv = *(const f16x4*)(pros + (size_t)(m0 + rb + 32 * ri) * 256 + kk);
      float x0 = (float)xv[0], x1 = (float)xv[1];
      float x2 = (float)xv[2], x3 = (float)xv[3];
#pragma unroll
      for (int cc = 0; cc < 4; ++cc)
        acc[ri][cc] += x0 * wv[cc].x + x1 * wv[cc].y + x2 * wv[cc].z + x3 * wv[cc].w;
    }
  }
#pragma unroll
  for (int cc = 0; cc < 4; ++cc) {
    float bias = bout[cg + 8 * cc];
#pragma unroll
    for (int ri = 0; ri < 8; ++ri)
      out[(size_t)(m0 + rb + 32 * ri) * BOT + cg + 8 * cc] = acc[ri][cc] + bias;
  }
}

extern "C" void kernel_launch(void* const* d_in, const int* in_sizes, int n_in,
                              void* d_out, int out_size, void* d_ws, size_t ws_size,
                              hipStream_t stream) {
  const float* x      = (const float*)d_in[0];
  const float* w_ih_f = (const float*)d_in[1];
  const float* w_hh_f = (const float*)d_in[2];
  const float* b_ih_f = (const float*)d_in[3];
  const float* b_hh_f = (const float*)d_in[4];
  const float* w_ih_b = (const float*)d_in[5];
  const float* w_hh_b = (const float*)d_in[6];
  const float* b_ih_b = (const float*)d_in[7];
  const float* b_hh_b = (const float*)d_in[8];
  const float* w_out  = (const float*)d_in[9];
  const float* b_out  = (const float*)d_in[10];
  float* out = (float*)d_out;

  // ws layout: gx f16 [65536][768] = 96 MiB, pros f16 [65536][256] = 32 MiB
  _Float16* gx   = (_Float16*)d_ws;
  _Float16* pros = (_Float16*)((char*)d_ws + (size_t)MM * GXC * sizeof(_Float16));

  gx_gemm<<<512, 256, 0, stream>>>(x, w_ih_f, w_ih_b, gx);
  gru_scan<<<128, 256, 0, stream>>>(gx, w_hh_f, w_hh_b, b_ih_f, b_hh_f,
                                    b_ih_b, b_hh_b, pros);
  out_proj<<<256, 256, 0, stream>>>(pros, w_out, b_out, out);
}

// Round 8
// 603.975 us; speedup vs baseline: 1.0943x; 1.0943x over previous
//
#include <hip/hip_runtime.h>

#define NB 64
#define TSTEPS 1024
#define EE 256
#define HH 128
#define MM (NB * TSTEPS)   // 65536 rows
#define GXC 768            // 384 fwd gates + 384 bwd gates
#define BOT 32
#define CH 16              // scan gx-staging chunk (steps)

typedef float    f32x4 __attribute__((ext_vector_type(4)));
typedef _Float16 f16x2 __attribute__((ext_vector_type(2)));
typedef _Float16 f16x4 __attribute__((ext_vector_type(4)));
typedef _Float16 f16x8 __attribute__((ext_vector_type(8)));

#if defined(__has_builtin)
#if __has_builtin(__builtin_amdgcn_rcpf)
#define HAVE_RCPF 1
#endif
#endif

__device__ __forceinline__ float rcpf(float x) {
#ifdef HAVE_RCPF
  return __builtin_amdgcn_rcpf(x);
#else
  return 1.0f / x;
#endif
}

// LDS-only barrier: orders LDS traffic (lgkmcnt) but does NOT drain vmcnt.
#define LDS_BARRIER() asm volatile("s_waitcnt lgkmcnt(0)\ns_barrier" ::: "memory")

// ---------------------------------------------------------------------------
// Kernel A: gx[m][g] = sum_e x[m][e]*w_ih[g][e].  Unchanged from R7.
// ---------------------------------------------------------------------------
__global__ __launch_bounds__(256, 1) void gx_gemm(
    const float* __restrict__ x, const float* __restrict__ wf,
    const float* __restrict__ wb, _Float16* __restrict__ gx) {
  __shared__ _Float16 As[128 * 264];   // x rows, K=256 + pad 8
  __shared__ _Float16 Bs[128 * 72];    // weight rows, 64-K chunk + pad 8
  const int tid = threadIdx.x;
  const int m0  = blockIdx.x * 128;

  const int lane = tid & 63;
  const int wid  = tid >> 6;
  const int wg = wid & 1, wm = wid >> 1;  // 2x2 wave grid: 64 g x 64 m
  const int l15  = lane & 15;
  const int quad = lane >> 4;
  const int fk   = quad * 8;

  // stage x-tile once: 128 rows x 64 float4
#pragma unroll
  for (int i = 0; i < 32; ++i) {
    int idx = tid + i * 256;          // 0..8191
    int row = idx >> 6;
    int kf  = (idx & 63) * 4;
    float4 av = *(const float4*)(x + (size_t)(m0 + row) * 256 + kf);
    f16x4 ah;
    ah[0] = (_Float16)av.x; ah[1] = (_Float16)av.y;
    ah[2] = (_Float16)av.z; ah[3] = (_Float16)av.w;
    *(f16x4*)&As[row * 264 + kf] = ah;
  }

#pragma unroll 1
  for (int by = 0; by < 6; ++by) {
    const float* wsrc = (by < 3) ? (wf + (size_t)(by * 128) * 256)
                                 : (wb + (size_t)((by - 3) * 128) * 256);
    const int g0 = by * 128;
    f32x4 acc[4][4];   // [tg][tmx]
#pragma unroll
    for (int a = 0; a < 4; ++a)
#pragma unroll
      for (int b = 0; b < 4; ++b) acc[a][b] = (f32x4)0.0f;

#pragma unroll 1
    for (int kc = 0; kc < 4; ++kc) {
      const int k0 = kc * 64;
      __syncthreads();   // protect Bs from previous use (also orders As once)
#pragma unroll
      for (int i = 0; i < 8; ++i) {
        int idx = tid + i * 256;        // 128 rows x 16 float4
        int row = idx >> 4;
        int k4  = (idx & 15) * 4;
        float4 bv = *(const float4*)(wsrc + (size_t)row * 256 + k0 + k4);
        f16x4 bh;
        bh[0] = (_Float16)bv.x; bh[1] = (_Float16)bv.y;
        bh[2] = (_Float16)bv.z; bh[3] = (_Float16)bv.w;
        *(f16x4*)&Bs[row * 72 + k4] = bh;
      }
      __syncthreads();
#pragma unroll
      for (int ks = 0; ks < 2; ++ks) {
        f16x8 wfr[4], xfr[4];
#pragma unroll
        for (int tt = 0; tt < 4; ++tt) {
          wfr[tt] = *(const f16x8*)&Bs[(wg * 64 + tt * 16 + l15) * 72 + ks * 32 + fk];
          xfr[tt] = *(const f16x8*)&As[(wm * 64 + tt * 16 + l15) * 264 + k0 + ks * 32 + fk];
        }
#pragma unroll
        for (int tg = 0; tg < 4; ++tg)
#pragma unroll
          for (int tmx = 0; tmx < 4; ++tmx)
            acc[tg][tmx] = __builtin_amdgcn_mfma_f32_16x16x32_f16(
                wfr[tg], xfr[tmx], acc[tg][tmx], 0, 0, 0);
      }
    }
    // epilogue: D[g][m] -> 4 consecutive g per lane -> f16x4 8B store
#pragma unroll
    for (int tg = 0; tg < 4; ++tg)
#pragma unroll
      for (int tmx = 0; tmx < 4; ++tmx) {
        int m = m0 + wm * 64 + tmx * 16 + l15;
        int g = g0 + wg * 64 + tg * 16 + quad * 4;
        f16x4 v;
        v[0] = (_Float16)acc[tg][tmx][0];
        v[1] = (_Float16)acc[tg][tmx][1];
        v[2] = (_Float16)acc[tg][tmx][2];
        v[3] = (_Float16)acc[tg][tmx][3];
        *(f16x4*)&gx[(size_t)m * GXC + g] = v;
      }
  }
}

// ---------------------------------------------------------------------------
// Kernel B: GRU scan — MFMA-broadcast matvec (R6 structure).
// R8: 16-step chunk body fully unrolled -> p = s&1 is compile-time, all
// hbuf/gbuf accesses become loop-invariant vaddr + immediate offsets;
// incremental pros offset; unpredicated LDS h-write (replicas write the
// same value to the same address — 2-way same-addr is free).
// ---------------------------------------------------------------------------
__global__ __launch_bounds__(256, 1) void gru_scan(
    const _Float16* __restrict__ gx,
    const float* __restrict__ whf, const float* __restrict__ whb,
    const float* __restrict__ bihf, const float* __restrict__ bhhf,
    const float* __restrict__ bihb, const float* __restrict__ bhhb,
    _Float16* __restrict__ pros) {
  const int bid = blockIdx.x;
  const int dir = bid & 1;
  const int n   = bid >> 1;
  const float* whh = dir ? whb : whf;
  const float* bih = dir ? bihb : bihf;
  const float* bhh = dir ? bhhb : bhhf;

  const int tid  = threadIdx.x;
  const int w    = tid >> 6;            // wave 0..3
  const int lane = tid & 63;
  const int l15  = lane & 15;
  const int quad = lane >> 4;           // 0..3
  const int jj   = (w << 5) | (lane & 31);   // h index; lanes 32-63 replicate

  __shared__ __align__(16) _Float16 hb[2 * 128];           // double-buffered h
  __shared__ __align__(16) _Float16 gbuf[2][CH * 384];     // 24 KB gx staging

  // B-frags: w_hh tiles, B[nrow = l15][k = quad*8 + j].
  // ti: 0,1 = r tile-pair; 2,3 = z; 4,5 = n.
  f16x8 bfrag[6][4];
#pragma unroll
  for (int ti = 0; ti < 6; ++ti) {
    const int nt  = (ti >> 1) * 8 + 2 * w + (ti & 1);
    const int row = nt * 16 + l15;
#pragma unroll
    for (int kt = 0; kt < 4; ++kt) {
      const int k0 = kt * 32 + quad * 8;
      float4 a = *(const float4*)(whh + (size_t)row * HH + k0);
      float4 b = *(const float4*)(whh + (size_t)row * HH + k0 + 4);
      f16x8 v;
      v[0] = (_Float16)a.x; v[1] = (_Float16)a.y;
      v[2] = (_Float16)a.z; v[3] = (_Float16)a.w;
      v[4] = (_Float16)b.x; v[5] = (_Float16)b.y;
      v[6] = (_Float16)b.z; v[7] = (_Float16)b.w;
      bfrag[ti][kt] = v;
    }
  }
  const float br  = bih[jj] + bhh[jj];
  const float bz  = bih[HH + jj] + bhh[HH + jj];
  const float bni = bih[2 * HH + jj];
  const float bnh = bhh[2 * HH + jj];
  const float LOG2E = 1.4426950408889634f;

  if (tid < 128) hb[tid] = (_Float16)0.f;
  float hprev = 0.f;

  // gx staging: 768 f16x8 units per chunk, 3 per thread
  f16x8 stage[3];
  int su[3], sc8[3];
#pragma unroll
  for (int i = 0; i < 3; ++i) {
    int u = tid + i * 256;
    su[i]  = u / 48;                 // step-in-chunk
    sc8[i] = (u - su[i] * 48) * 8;   // half-offset within the 384-col row
  }
  auto load_chunk = [&](int ch) {
#pragma unroll
    for (int i = 0; i < 3; ++i) {
      int t  = ch * CH + su[i];
      int tt = dir ? (TSTEPS - 1 - t) : t;
      stage[i] = *(const f16x8*)(gx + ((size_t)(n * TSTEPS + tt)) * GXC +
                                 dir * 384 + sc8[i]);
    }
  };
  auto write_chunk = [&](int buf) {
#pragma unroll
    for (int i = 0; i < 3; ++i)
      *(f16x8*)&gbuf[buf][su[i] * 384 + sc8[i]] = stage[i];
  };

  load_chunk(0);
  write_chunk(0);
  LDS_BARRIER();

  // incremental pros offset: elements, step stride = +-EE
  int poff = (n * TSTEPS + (dir ? (TSTEPS - 1) : 0)) * EE + dir * HH + jj;
  const int pstep = dir ? -EE : EE;

  const f32x4 zacc = (f32x4)0.0f;
  const int b4 = (lane >> 4) & 1;        // tile-pair select for this lane
  const int NCH = TSTEPS / CH;
#pragma unroll 1
  for (int ch = 0; ch < NCH; ++ch) {
    if (ch + 1 < NCH) load_chunk(ch + 1);  // into regs; retires mid-chunk
    const _Float16* gb = gbuf[ch & 1];     // runtime base, imm offsets below
#pragma unroll
    for (int s = 0; s < CH; ++s) {
      const int p = s & 1;                 // compile-time under full unroll
      // gx reads: base vaddr (2*jj) + immediate offsets
      const float pxr = -((float)gb[s * 384 + jj] + br) * LOG2E;
      const float pxz = -((float)gb[s * 384 + HH + jj] + bz) * LOG2E;
      const float pxn = (float)gb[s * 384 + 2 * HH + jj] + bni;
      // A-frags: h broadcast; vaddr = quad*16, imm = p*256 + kt*64
      f16x8 af[4];
#pragma unroll
      for (int kt = 0; kt < 4; ++kt)
        af[kt] = *(const f16x8*)&hb[p * 128 + kt * 32 + quad * 8];
      // 6 N-tiles x 4 K-tiles of MFMA (M-replicated h)
      f32x4 d[6];
#pragma unroll
      for (int ti = 0; ti < 6; ++ti) {
        d[ti] = __builtin_amdgcn_mfma_f32_16x16x32_f16(af[0], bfrag[ti][0],
                                                       zacc, 0, 0, 0);
#pragma unroll
        for (int kt = 1; kt < 4; ++kt)
          d[ti] = __builtin_amdgcn_mfma_f32_16x16x32_f16(af[kt], bfrag[ti][kt],
                                                         d[ti], 0, 0, 0);
      }
      // per-lane gate sums: tile-pair select by bit4 (all m-replicas equal)
      const float ar = b4 ? d[1][0] : d[0][0];
      const float az = b4 ? d[3][0] : d[2][0];
      const float an = b4 ? d[5][0] : d[4][0];
      // tail (redundant in replica lanes)
      const float rv = rcpf(1.f + __builtin_exp2f(fmaf(ar, -LOG2E, pxr)));
      const float zv = rcpf(1.f + __builtin_exp2f(fmaf(az, -LOG2E, pxz)));
      float na = fmaf(rv, an + bnh, pxn);
      na = fminf(15.f, fmaxf(-15.f, na));
      const float e  = __builtin_exp2f(na * (-2.f * LOG2E));
      const float nn = (1.f - e) * rcpf(1.f + e);
      const float hnew = fmaf(zv, hprev - nn, nn);   // (1-z)*n + z*h
      hprev = hnew;
      const _Float16 hh16 = (_Float16)hnew;
      hb[(p ^ 1) * 128 + jj] = hh16;       // all lanes; replicas same addr+val
      if (lane < 32) pros[poff] = hh16;
      poff += pstep;
      if (s == 7 && ch + 1 < NCH) write_chunk((ch & 1) ^ 1);  // vmcnt retired
      LDS_BARRIER();
    }
  }
}

// ---------------------------------------------------------------------------
// Kernel C: out[m][o] = pros[m][:] . w_out[o][:] + b_out[o]
// Unchanged from R7.
// ---------------------------------------------------------------------------
__global__ __launch_bounds__(256) void out_proj(
    const _Float16* __restrict__ pros, const float* __restrict__ wout,
    const float* __restrict__ bout, float* __restrict__ out) {
  __shared__ float wlds[32 * 260];
  const int tid = threadIdx.x;
  const int m0  = blockIdx.x * 256;
#pragma unroll
  for (int i = 0; i < 8; ++i) {
    int f4  = tid + i * 256;   // 0..2047 float4s of w_out
    int col = f4 >> 6;
    int k4  = (f4 & 63) * 4;
    *(float4*)&wlds[col * 260 + k4] = *(const float4*)(wout + (size_t)col * 256 + k4);
  }
  __syncthreads();
  const int rb = tid >> 3;  // 0..31
  const int cg = tid & 7;   // 0..7
  float acc[8][4];
#pragma unroll
  for (int a = 0; a < 8; ++a)
#pragma unroll
    for (int b = 0; b < 4; ++b) acc[a][b] = 0.f;

  for (int kk = 0; kk < 256; kk += 4) {
    float4 wv[4];
#pragma unroll
    for (int cc = 0; cc < 4; ++cc)
      wv[cc] = *(const float4*)&wlds[(cg + 8 * cc) * 260 + kk];
#pragma unroll
    for (int ri = 0; ri < 8; ++ri) {
      f16x4 xv = *(const f16x4*)(pros + (size_t)(m0 + rb + 32 * ri) * 256 + kk);
      float x0 = (float)xv[0], x1 = (float)xv[1];
      float x2 = (float)xv[2], x3 = (float)xv[3];
#pragma unroll
      for (int cc = 0; cc < 4; ++cc)
        acc[ri][cc] += x0 * wv[cc].x + x1 * wv[cc].y + x2 * wv[cc].z + x3 * wv[cc].w;
    }
  }
#pragma unroll
  for (int cc = 0; cc < 4; ++cc) {
    float bias = bout[cg + 8 * cc];
#pragma unroll
    for (int ri = 0; ri < 8; ++ri)
      out[(size_t)(m0 + rb + 32 * ri) * BOT + cg + 8 * cc] = acc[ri][cc] + bias;
  }
}

extern "C" void kernel_launch(void* const* d_in, const int* in_sizes, int n_in,
                              void* d_out, int out_size, void* d_ws, size_t ws_size,
                              hipStream_t stream) {
  const float* x      = (const float*)d_in[0];
  const float* w_ih_f = (const float*)d_in[1];
  const float* w_hh_f = (const float*)d_in[2];
  const float* b_ih_f = (const float*)d_in[3];
  const float* b_hh_f = (const float*)d_in[4];
  const float* w_ih_b = (const float*)d_in[5];
  const float* w_hh_b = (const float*)d_in[6];
  const float* b_ih_b = (const float*)d_in[7];
  const float* b_hh_b = (const float*)d_in[8];
  const float* w_out  = (const float*)d_in[9];
  const float* b_out  = (const float*)d_in[10];
  float* out = (float*)d_out;

  // ws layout: gx f16 [65536][768] = 96 MiB, pros f16 [65536][256] = 32 MiB
  _Float16* gx   = (_Float16*)d_ws;
  _Float16* pros = (_Float16*)((char*)d_ws + (size_t)MM * GXC * sizeof(_Float16));

  gx_gemm<<<512, 256, 0, stream>>>(x, w_ih_f, w_ih_b, gx);
  gru_scan<<<128, 256, 0, stream>>>(gx, w_hh_f, w_hh_b, b_ih_f, b_hh_f,
                                    b_ih_b, b_hh_b, pros);
  out_proj<<<256, 256, 0, stream>>>(pros, w_out, b_out, out);
}